// Round 6
// baseline (159.617 us; speedup 1.0000x reference)
//
#include <hip/hip_runtime.h>

#define NAQ 35
#define NME 18
#define NN  53
#define FD  64
#define CTXD 60
#define WAVES 8

typedef unsigned int   u32;
typedef unsigned short u16;
typedef short s8v __attribute__((ext_vector_type(8)));
typedef float f4v __attribute__((ext_vector_type(4)));

// ---- ws layout ----
//  u16 [0,2048)      : WtA  u16[64][32]  Wt[n][k] = k<16 ? Wxa[k][n] : Wxm[k-16][n]
//  u16 [2048,2304)   : WtP hi u16[4][64] proj weights (pre-scaled by log2e), bf16 high
//  u16 [2304,2560)   : WtP lo u16[4][64] bf16 residual
//  f32 [1280,5376)   : EB2 f32[64][64]   masked bias+ctx dots, log2e-scaled; sentinel 1e30
//  f32 [5376]        : bf16-input flag
#define WS_EB_F  1280
#define WS_FLAG  5376
#define LOG2E    1.44269504f

__device__ __forceinline__ float ldf(const void* p, long i, bool bf) {
  if (bf) { u16 h = ((const u16*)p)[i]; return __uint_as_float(((u32)h) << 16); }
  return ((const float*)p)[i];
}
__device__ __forceinline__ u16 f2bf(float f) {
  u32 u = __float_as_uint(f);
  return (u16)((u + 0x7FFFu + ((u >> 16) & 1u)) >> 16);
}
__device__ __forceinline__ float bf2f(u16 h) {
  return __uint_as_float(((u32)h) << 16);
}
__device__ __forceinline__ u32 pk2(float a, float b) {
  return (u32)f2bf(a) | ((u32)f2bf(b) << 16);
}
__device__ __forceinline__ bool sniff_bf16(const void* ctx) {
  const u32* w = (const u32*)ctx;
  bool ok = true;
#pragma unroll
  for (int k = 0; k < 32; ++k) {
    u32 e = (w[k] >> 7) & 0xFFu;
    ok = ok && (e >= 96u && e <= 160u);
  }
  return ok;
}
__device__ __forceinline__ s8v ld_fragu(const u16* p) {
  union { float4 f; s8v s; } u;
  u.f = *(const float4*)(const void*)p;
  return u.s;
}
__device__ __forceinline__ s8v pack8f(float4 a, float4 b) {
  union { u32 u[4]; s8v s; } U;
  U.u[0] = pk2(a.x, a.y);
  U.u[1] = pk2(a.z, a.w);
  U.u[2] = pk2(b.x, b.y);
  U.u[3] = pk2(b.z, b.w);
  return U.s;
}
__device__ __forceinline__ s8v load_inp8(const void* p, long idx, bool bf) {
  if (bf) {
    union { uint4 u; s8v s; } U;
    U.u = *(const uint4*)((const u16*)p + idx);
    return U.s;
  }
  float4 f0 = *(const float4*)((const float*)p + idx);
  float4 f1 = *(const float4*)((const float*)p + idx + 4);
  return pack8f(f0, f1);
}
__device__ __forceinline__ void pack_hl(const float* e, s8v* hi, s8v* lo) {
  union { u32 u[4]; s8v s; } H, L;
#pragma unroll
  for (int w = 0; w < 4; ++w) {
    u16 h0 = f2bf(e[2*w]), h1 = f2bf(e[2*w+1]);
    float l0 = e[2*w] - bf2f(h0), l1 = e[2*w+1] - bf2f(h1);
    H.u[w] = (u32)h0 | ((u32)h1 << 16);
    L.u[w] = (u32)f2bf(l0) | ((u32)f2bf(l1) << 16);
  }
  *hi = H.s; *lo = L.s;
}
__device__ __forceinline__ void avsel(int tr,
    const void* a_aa, const void* a_am, const void* a_ma, const void* a_mm,
    const void** av, int* off) {
  switch (tr) {
    case 0: *av = a_aa; *off = 0;   break;
    case 1: *av = a_am; *off = 0;   break;
    case 2: *av = a_aa; *off = 124; break;
    case 3: *av = a_ma; *off = 124; break;
    case 4: *av = a_ma; *off = 0;   break;
    case 5: *av = a_mm; *off = 0;   break;
    case 6: *av = a_am; *off = 124; break;
    default:*av = a_mm; *off = 124; break;
  }
}

// =======================================================================
// prep: batch-invariant tables -> ws
// =======================================================================
__global__ void prep_kernel(
    const void* __restrict__ ctx, const void* __restrict__ adjn,
    const void* __restrict__ Wxa, const void* __restrict__ Wxm,
    const void* __restrict__ Wua, const void* __restrict__ Wum,
    const void* __restrict__ a_aa, const void* __restrict__ a_am,
    const void* __restrict__ a_ma, const void* __restrict__ a_mm,
    const int* __restrict__ adj, float* __restrict__ ws)
{
  const bool bf = sniff_bf16(ctx);
  int tid = blockIdx.x * blockDim.x + threadIdx.x;
  if (tid == 0) ws[WS_FLAG] = bf ? 1.f : 0.f;
  if (tid < 2048) {                        // WtA[n][k] bf16 (NOT scaled)
    int n = tid >> 5, kk = tid & 31;
    float v = (kk < 16) ? ldf(Wxa, kk * 64 + n, bf)
                        : ldf(Wxm, (kk - 16) * 64 + n, bf);
    ((u16*)ws)[tid] = f2bf(v);
    return;
  }
  if (tid < 2560) {                        // WtP hi/lo: proj weights * log2e
    int idx = tid - 2048;
    int half = idx >> 8, rem = idx & 255;
    int role = rem >> 6, k = rem & 63;
    float w = 0.f;
    const void* Wu = nullptr; int kk = -1, tr = 0;
    if (k < 16)      { Wu = Wua; kk = k;           tr = role;     }
    else if (k < 32) { Wu = Wum; kk = k - 16;      tr = 4 + role; }
    else if (k < 40) { Wu = Wua; kk = 16 + (k-32); tr = role;     }
    else if (k < 50) { Wu = Wum; kk = 16 + (k-40); tr = 4 + role; }
    if (kk >= 0) {
      const void* av; int off;
      avsel(tr, a_aa, a_am, a_ma, a_mm, &av, &off);
      float s = 0.f;
      for (int f = 0; f < 64; ++f) s += ldf(Wu, kk * 64 + f, bf) * ldf(av, off + f, bf);
      w = s * LOG2E;
    }
    u16 hi = f2bf(w);
    u16 val = hi;
    if (half) { float lo = w - bf2f(hi); val = f2bf(lo); }
    ((u16*)ws)[2048 + idx] = val;
    return;
  }
  if (tid < 6656) {                        // EB2[r][j] (64 rows): (bias+ctx)*log2e
    int e = tid - 2560;
    int r = e >> 6, j = e & 63;
    float v = 1e30f;
    if (r < NN && j < NN && adj[r * NN + j] > 0) {
      const void* aq = (r < NAQ) ? ((j < NAQ) ? a_aa : a_am)
                                 : ((j < NAQ) ? a_ma : a_mm);
      float s = ldf(adjn, r * NN + j, bf) * ldf(aq, 248, bf);
      for (int c = 0; c < CTXD; ++c) {
        s += ldf(ctx, r * CTXD + c, bf) * ldf(aq, 64 + c, bf);
        s += ldf(ctx, j * CTXD + c, bf) * ldf(aq, 188 + c, bf);
      }
      v = s * LOG2E;
    }
    ws[WS_EB_F + e] = v;
  }
}

// =======================================================================
// main: one WAVE = one batch element; NO block-wide barrier at all.
// Tables (WtA/WtP/EB) read straight from ws (L1/L2-hot, shared by all
// blocks). Only sSVW (wave-private proj scatter) lives in LDS.
// =======================================================================
__global__ __launch_bounds__(512, 4) void hga_main(
    const void* __restrict__ aqi_inp, const void* __restrict__ meo_inp,
    const void* __restrict__ ctx,
    const void* __restrict__ aqi_idE, const void* __restrict__ aqi_monthE,
    const void* __restrict__ aqi_weekdayE, const void* __restrict__ aqi_hourE,
    const void* __restrict__ meo_windE, const void* __restrict__ meo_idE,
    const void* __restrict__ meo_monthE, const void* __restrict__ meo_weekdayE,
    const void* __restrict__ meo_hourE,
    const int* __restrict__ aqi_ex, const int* __restrict__ meo_ex,
    const float* __restrict__ ws, void* __restrict__ out, int B)
{
  __shared__ __align__(16) float sSVW[WAVES * 256]; // per wave: S[64][2] then T[64][2]

  const int t = threadIdx.x;
  const bool bf = (ws[WS_FLAG] != 0.f);   // uniform scalar load (prep-written)
  const int wv = t >> 6, lane = t & 63;
  const int mm = lane & 15, q4 = lane >> 4;
  const int b = blockIdx.x * WAVES + wv;
  if (b >= B) return;

  // ---- A-fragments straight from global ----
  s8v av0[4], a1h[4], a1l[4];
  const s8v zero8 = {0, 0, 0, 0, 0, 0, 0, 0};
#pragma unroll
  for (int i = 0; i < 4; ++i) {
    const int r = 16 * i + mm;
    s8v v0 = zero8, vh = zero8, vl = zero8;
    if (r < NN) {
      if (r < NAQ) {
        if (q4 < 2) v0 = load_inp8(aqi_inp, ((long)b * NAQ + r) * 16 + q4 * 8, bf);
        if (q4 == 0) {                       // aqi emb dims 0..7 (k 32..39)
          const int4 ix = *(const int4*)(aqi_ex + ((long)b * NAQ + r) * 4);
          float e[8];
          e[0] = ldf(aqi_idE,      ix.x * 2, bf);  e[1] = ldf(aqi_idE,      ix.x * 2 + 1, bf);
          e[2] = ldf(aqi_monthE,   ix.y * 2, bf);  e[3] = ldf(aqi_monthE,   ix.y * 2 + 1, bf);
          e[4] = ldf(aqi_weekdayE, ix.z * 2, bf);  e[5] = ldf(aqi_weekdayE, ix.z * 2 + 1, bf);
          e[6] = ldf(aqi_hourE,    ix.w * 2, bf);  e[7] = ldf(aqi_hourE,    ix.w * 2 + 1, bf);
          pack_hl(e, &vh, &vl);
        }
      } else {
        const int ri = r - NAQ;
        if (q4 >= 2) v0 = load_inp8(meo_inp, ((long)b * NME + ri) * 16 + (q4 - 2) * 8, bf);
        if (q4 == 1) {                       // meo emb dims 0..7 (k 40..47)
          const int* ix = meo_ex + ((long)b * NME + ri) * 5;
          float e[8];
          e[0] = ldf(meo_windE,    ix[0] * 2, bf); e[1] = ldf(meo_windE,    ix[0] * 2 + 1, bf);
          e[2] = ldf(meo_idE,      ix[1] * 2, bf); e[3] = ldf(meo_idE,      ix[1] * 2 + 1, bf);
          e[4] = ldf(meo_monthE,   ix[2] * 2, bf); e[5] = ldf(meo_monthE,   ix[2] * 2 + 1, bf);
          e[6] = ldf(meo_weekdayE, ix[3] * 2, bf); e[7] = ldf(meo_weekdayE, ix[3] * 2 + 1, bf);
          pack_hl(e, &vh, &vl);
        } else if (q4 == 2) {                // meo emb dims 8..9 (k 48..49)
          int i4 = meo_ex[((long)b * NME + ri) * 5 + 4];
          float e[8] = {0.f, 0.f, 0.f, 0.f, 0.f, 0.f, 0.f, 0.f};
          e[0] = ldf(meo_hourE, i4 * 2, bf);  e[1] = ldf(meo_hourE, i4 * 2 + 1, bf);
          pack_hl(e, &vh, &vl);
        }
      }
    }
    av0[i] = v0; a1h[i] = vh; a1l[i] = vl;
  }

  const u16* wsu  = (const u16*)ws;
  const u16* wphi = wsu + 2048;
  const u16* wplo = wsu + 2304;

  // ---- projections via MFMA (hi/lo split weights, L1-hot global reads) ----
  {
    s8v bh0 = ld_fragu(wphi + mm * 64 + q4 * 8);
    s8v bh1 = ld_fragu(wphi + mm * 64 + 32 + q4 * 8);
    s8v bl0 = ld_fragu(wplo + mm * 64 + q4 * 8);
    s8v bl1 = ld_fragu(wplo + mm * 64 + 32 + q4 * 8);
    f4v pacc[4];
#pragma unroll
    for (int i = 0; i < 4; ++i) {
      f4v a = {0.f, 0.f, 0.f, 0.f};
      a = __builtin_amdgcn_mfma_f32_16x16x32_bf16(av0[i], bh0, a, 0, 0, 0);
      a = __builtin_amdgcn_mfma_f32_16x16x32_bf16(av0[i], bl0, a, 0, 0, 0);
      a = __builtin_amdgcn_mfma_f32_16x16x32_bf16(a1h[i], bh1, a, 0, 0, 0);
      a = __builtin_amdgcn_mfma_f32_16x16x32_bf16(a1h[i], bl1, a, 0, 0, 0);
      if (!bf)
        a = __builtin_amdgcn_mfma_f32_16x16x32_bf16(a1l[i], bh1, a, 0, 0, 0);
      pacc[i] = a;
    }
    // scatter projections to this wave's svw slice (roles: mm 0..3)
    if (mm < 4) {
      float* wbase = sSVW + wv * 256 + ((mm >= 2) ? 128 : 0) + (mm & 1);
#pragma unroll
      for (int i = 0; i < 4; ++i)
#pragma unroll
        for (int reg = 0; reg < 4; ++reg) {
          int row = 16 * i + q4 * 4 + reg;
          wbase[row * 2] = pacc[i][reg];
        }
    }
  }
  asm volatile("s_waitcnt lgkmcnt(0)" ::: "memory");   // wave-internal ordering only
  __builtin_amdgcn_sched_barrier(0);

  // ---- softmax fully in-register (exp2 domain), GEMM2 B-frag layout ----
  const float* sv = sSVW + wv * 256;
  u32 paw[4][8];
#pragma unroll
  for (int i = 0; i < 4; ++i) {
    const int r = 16 * i + mm;
    const bool rA = (r < NAQ);
    const int tsel = rA ? 0 : 1;
    float2 sp = *(const float2*)(sv + r * 2);
    const float* ebr = ws + WS_EB_F + r * 64;          // L1/L2-hot global
    float4 ea  = *(const float4*)(ebr + q4 * 8);
    float4 eb_ = *(const float4*)(ebr + q4 * 8 + 4);
    float4 ec  = *(const float4*)(ebr + 32 + q4 * 8);
    float4 ed  = *(const float4*)(ebr + 32 + q4 * 8 + 4);
    float ebv[16] = {ea.x, ea.y, ea.z, ea.w, eb_.x, eb_.y, eb_.z, eb_.w,
                     ec.x, ec.y, ec.z, ec.w, ed.x, ed.y, ed.z, ed.w};
    float v[16];
    float m = -3.0e38f;
#pragma unroll
    for (int c = 0; c < 16; ++c) {
      const int j = (c < 8) ? (q4 * 8 + c) : (32 + q4 * 8 + (c - 8));
      float s = (j < NAQ) ? sp.x : sp.y;
      float tv = sv[128 + j * 2 + tsel];
      float x = s + tv + ebv[c];
      float lk = fmaxf(x, 0.2f * x);
      float val = (ebv[c] > 1e29f) ? -1.0e12f : lk;
      v[c] = val;
      m = fmaxf(m, val);
    }
    m = fmaxf(m, __shfl_xor(m, 16));
    m = fmaxf(m, __shfl_xor(m, 32));
    float sum = 0.f;
#pragma unroll
    for (int c = 0; c < 16; ++c) { float p = exp2f(v[c] - m); v[c] = p; sum += p; }
    sum += __shfl_xor(sum, 16);
    sum += __shfl_xor(sum, 32);
    const float rinv = 1.f / sum;
#pragma unroll
    for (int w = 0; w < 8; ++w) {
      const int c0 = (w >> 2) * 8 + (w & 3) * 2;
      paw[i][w] = pk2(v[c0] * rinv, v[c0 + 1] * rinv);
    }
  }

  // ---- GEMM1 (attri) + in-register transpose + swapped GEMM2 (O^T) ----
  const u32 baseA = (u32)b * (NAQ * 64u);
  const u32 baseM = (u32)B * (NAQ * 64u) + (u32)b * (NME * 64u);
  const int srcA = (2 * (q4 & 1)) * 16 + mm;
  const int srcB = srcA + 16;
  const bool hs = (q4 >= 2);
  __builtin_amdgcn_s_setprio(1);
#pragma unroll
  for (int nt = 0; nt < 4; ++nt) {
    s8v bw = ld_fragu(wsu + (16 * nt + mm) * 32 + q4 * 8);   // WtA, L1-hot
    f4v ag[4];
#pragma unroll
    for (int i = 0; i < 4; ++i) {
      f4v z = {0.f, 0.f, 0.f, 0.f};
      ag[i] = __builtin_amdgcn_mfma_f32_16x16x32_bf16(av0[i], bw, z, 0, 0, 0);
    }
    u32 p0[4], p1[4];
#pragma unroll
    for (int i = 0; i < 4; ++i) {
      p0[i] = pk2(ag[i][0], ag[i][1]);
      p1[i] = pk2(ag[i][2], ag[i][3]);
    }
    union { u32 u[4]; s8v s; } W0, W1;
    u32 x0, x1;
    x0 = (u32)__shfl((int)p0[0], srcA); x1 = (u32)__shfl((int)p0[1], srcA); W0.u[0] = hs ? x1 : x0;
    x0 = (u32)__shfl((int)p1[0], srcA); x1 = (u32)__shfl((int)p1[1], srcA); W0.u[1] = hs ? x1 : x0;
    x0 = (u32)__shfl((int)p0[0], srcB); x1 = (u32)__shfl((int)p0[1], srcB); W0.u[2] = hs ? x1 : x0;
    x0 = (u32)__shfl((int)p1[0], srcB); x1 = (u32)__shfl((int)p1[1], srcB); W0.u[3] = hs ? x1 : x0;
    x0 = (u32)__shfl((int)p0[2], srcA); x1 = (u32)__shfl((int)p0[3], srcA); W1.u[0] = hs ? x1 : x0;
    x0 = (u32)__shfl((int)p1[2], srcA); x1 = (u32)__shfl((int)p1[3], srcA); W1.u[1] = hs ? x1 : x0;
    x0 = (u32)__shfl((int)p0[2], srcB); x1 = (u32)__shfl((int)p0[3], srcB); W1.u[2] = hs ? x1 : x0;
    x0 = (u32)__shfl((int)p1[2], srcB); x1 = (u32)__shfl((int)p1[3], srcB); W1.u[3] = hs ? x1 : x0;
    s8v bt0 = W0.s, bt1 = W1.s;
#pragma unroll
    for (int i = 0; i < 4; ++i) {
      union { u32 u[4]; s8v s; } A0, A1;
      A0.u[0] = paw[i][0]; A0.u[1] = paw[i][1]; A0.u[2] = paw[i][2]; A0.u[3] = paw[i][3];
      A1.u[0] = paw[i][4]; A1.u[1] = paw[i][5]; A1.u[2] = paw[i][6]; A1.u[3] = paw[i][7];
      f4v acc = {0.f, 0.f, 0.f, 0.f};
      acc = __builtin_amdgcn_mfma_f32_16x16x32_bf16(bt0, A0.s, acc, 0, 0, 0);
      acc = __builtin_amdgcn_mfma_f32_16x16x32_bf16(bt1, A1.s, acc, 0, 0, 0);
      const int r = 16 * i + mm;
      if (r < NN) {
        u32 off = ((r < NAQ) ? (baseA + (u32)r * 64u)
                             : (baseM + (u32)(r - NAQ) * 64u))
                  + 16u * (u32)nt + (u32)(q4 * 4);
        if (bf) {
          uint2 pkv;
          pkv.x = pk2(acc[0], acc[1]);
          pkv.y = pk2(acc[2], acc[3]);
          *(uint2*)((u16*)out + off) = pkv;
        } else {
          union { f4v v; float4 f; } cv; cv.v = acc;
          *(float4*)((float*)out + off) = cv.f;
        }
      }
    }
  }
  __builtin_amdgcn_s_setprio(0);
}

extern "C" void kernel_launch(void* const* d_in, const int* in_sizes, int n_in,
                              void* d_out, int out_size, void* d_ws, size_t ws_size,
                              hipStream_t stream)
{
  const void* aqi_inp      = d_in[0];
  const void* meo_inp      = d_in[1];
  const void* ctx          = d_in[2];
  const void* adjn         = d_in[3];
  const void* aqi_idE      = d_in[4];
  const void* aqi_monthE   = d_in[5];
  const void* aqi_weekdayE = d_in[6];
  const void* aqi_hourE    = d_in[7];
  const void* meo_windE    = d_in[8];
  const void* meo_idE      = d_in[9];
  const void* meo_monthE   = d_in[10];
  const void* meo_weekdayE = d_in[11];
  const void* meo_hourE    = d_in[12];
  const void* Wxa          = d_in[13];
  const void* Wxm          = d_in[14];
  const void* Wua          = d_in[15];
  const void* Wum          = d_in[16];
  const void* a_aa         = d_in[17];
  const void* a_am         = d_in[18];
  const void* a_ma         = d_in[19];
  const void* a_mm         = d_in[20];
  const int*  aqi_ex       = (const int*)d_in[21];
  const int*  meo_ex       = (const int*)d_in[22];
  float* ws = (float*)d_ws;
  const int B = in_sizes[0] / (NAQ * 16);

  hipLaunchKernelGGL(prep_kernel, dim3((6656 + 255) / 256), dim3(256), 0, stream,
                     ctx, adjn, Wxa, Wxm, Wua, Wum, a_aa, a_am, a_ma, a_mm,
                     (const int*)d_in[23], ws);
  hipLaunchKernelGGL(hga_main, dim3((B + WAVES - 1) / WAVES), dim3(512), 0, stream,
                     aqi_inp, meo_inp, ctx, aqi_idE, aqi_monthE, aqi_weekdayE, aqi_hourE,
                     meo_windE, meo_idE, meo_monthE, meo_weekdayE, meo_hourE,
                     aqi_ex, meo_ex, ws, d_out, B);
}

// Round 7
// 152.580 us; speedup vs baseline: 1.0461x; 1.0461x over previous
//
#include <hip/hip_runtime.h>

#define NAQ 35
#define NME 18
#define NN  53
#define FD  64
#define CTXD 60
#define WAVES 8

typedef unsigned int   u32;
typedef unsigned short u16;
typedef short s8v __attribute__((ext_vector_type(8)));
typedef float f4v __attribute__((ext_vector_type(4)));

// ---- ws float layout ----
//  [0,1024)    : WtA  u16[64][32]   Wt[n][k] = k<16 ? Wxa[k][n] : Wxm[k-16][n]
//  [1024,1152) : WtP hi u16[4][64]  proj weights * log2e, bf16 high
//  [1152,1280) : WtP lo u16[4][64]  bf16 residual
//  [1280,4672) : EB2 f32[53][64]    (bias + ctx dots) * log2e; sentinel 1e30
//  [4672]      : bf16-input flag
#define WS_EB_F  1280
#define WS_FLAG  4672
#define LOG2E    1.44269504f

__device__ __forceinline__ float ldf(const void* p, long i, bool bf) {
  if (bf) { u16 h = ((const u16*)p)[i]; return __uint_as_float(((u32)h) << 16); }
  return ((const float*)p)[i];
}
__device__ __forceinline__ u16 f2bf(float f) {
  u32 u = __float_as_uint(f);
  return (u16)((u + 0x7FFFu + ((u >> 16) & 1u)) >> 16);
}
__device__ __forceinline__ float bf2f(u16 h) {
  return __uint_as_float(((u32)h) << 16);
}
__device__ __forceinline__ u32 pk2(float a, float b) {
  return (u32)f2bf(a) | ((u32)f2bf(b) << 16);
}
__device__ __forceinline__ bool sniff_bf16(const void* ctx) {
  const u32* w = (const u32*)ctx;
  bool ok = true;
#pragma unroll
  for (int k = 0; k < 32; ++k) {
    u32 e = (w[k] >> 7) & 0xFFu;
    ok = ok && (e >= 96u && e <= 160u);
  }
  return ok;
}
__device__ __forceinline__ s8v ld_fragu(const u16* p) {
  union { float4 f; s8v s; } u;
  u.f = *(const float4*)(const void*)p;
  return u.s;
}
__device__ __forceinline__ s8v pack8f(float4 a, float4 b) {
  union { u32 u[4]; s8v s; } U;
  U.u[0] = pk2(a.x, a.y);
  U.u[1] = pk2(a.z, a.w);
  U.u[2] = pk2(b.x, b.y);
  U.u[3] = pk2(b.z, b.w);
  return U.s;
}
__device__ __forceinline__ s8v load_inp8(const void* p, long idx, bool bf) {
  if (bf) {
    union { uint4 u; s8v s; } U;
    U.u = *(const uint4*)((const u16*)p + idx);
    return U.s;
  }
  float4 f0 = *(const float4*)((const float*)p + idx);
  float4 f1 = *(const float4*)((const float*)p + idx + 4);
  return pack8f(f0, f1);
}
__device__ __forceinline__ void pack_hl(const float* e, s8v* hi, s8v* lo) {
  union { u32 u[4]; s8v s; } H, L;
#pragma unroll
  for (int w = 0; w < 4; ++w) {
    u16 h0 = f2bf(e[2*w]), h1 = f2bf(e[2*w+1]);
    float l0 = e[2*w] - bf2f(h0), l1 = e[2*w+1] - bf2f(h1);
    H.u[w] = (u32)h0 | ((u32)h1 << 16);
    L.u[w] = (u32)f2bf(l0) | ((u32)f2bf(l1) << 16);
  }
  *hi = H.s; *lo = L.s;
}
__device__ __forceinline__ void avsel(int tr,
    const void* a_aa, const void* a_am, const void* a_ma, const void* a_mm,
    const void** av, int* off) {
  switch (tr) {
    case 0: *av = a_aa; *off = 0;   break;
    case 1: *av = a_am; *off = 0;   break;
    case 2: *av = a_aa; *off = 124; break;
    case 3: *av = a_ma; *off = 124; break;
    case 4: *av = a_ma; *off = 0;   break;
    case 5: *av = a_mm; *off = 0;   break;
    case 6: *av = a_am; *off = 124; break;
    default:*av = a_mm; *off = 124; break;
  }
}

// =======================================================================
// prep: batch-invariant tables -> ws
// =======================================================================
__global__ void prep_kernel(
    const void* __restrict__ ctx, const void* __restrict__ adjn,
    const void* __restrict__ Wxa, const void* __restrict__ Wxm,
    const void* __restrict__ Wua, const void* __restrict__ Wum,
    const void* __restrict__ a_aa, const void* __restrict__ a_am,
    const void* __restrict__ a_ma, const void* __restrict__ a_mm,
    const int* __restrict__ adj, float* __restrict__ ws)
{
  const bool bf = sniff_bf16(ctx);
  int tid = blockIdx.x * blockDim.x + threadIdx.x;
  if (tid == 0) ws[WS_FLAG] = bf ? 1.f : 0.f;
  if (tid < 2048) {                        // WtA[n][k] bf16 (NOT scaled)
    int n = tid >> 5, kk = tid & 31;
    float v = (kk < 16) ? ldf(Wxa, kk * 64 + n, bf)
                        : ldf(Wxm, (kk - 16) * 64 + n, bf);
    ((u16*)ws)[tid] = f2bf(v);
    return;
  }
  if (tid < 2560) {                        // WtP hi/lo: proj weights * log2e
    int idx = tid - 2048;
    int half = idx >> 8, rem = idx & 255;
    int role = rem >> 6, k = rem & 63;
    float w = 0.f;
    const void* Wu = nullptr; int kk = -1, tr = 0;
    if (k < 16)      { Wu = Wua; kk = k;           tr = role;     }
    else if (k < 32) { Wu = Wum; kk = k - 16;      tr = 4 + role; }
    else if (k < 40) { Wu = Wua; kk = 16 + (k-32); tr = role;     }
    else if (k < 50) { Wu = Wum; kk = 16 + (k-40); tr = 4 + role; }
    if (kk >= 0) {
      const void* av; int off;
      avsel(tr, a_aa, a_am, a_ma, a_mm, &av, &off);
      float s = 0.f;
      for (int f = 0; f < 64; ++f) s += ldf(Wu, kk * 64 + f, bf) * ldf(av, off + f, bf);
      w = s * LOG2E;
    }
    u16 hi = f2bf(w);
    u16 val = hi;
    if (half) { float lo = w - bf2f(hi); val = f2bf(lo); }
    ((u16*)ws)[2048 + idx] = val;
    return;
  }
  if (tid < 5952) {                        // EB2[r][j]: (bias + ctx dots) * log2e
    int e = tid - 2560;
    int r = e >> 6, j = e & 63;
    float v = 1e30f;
    if (j < NN && adj[r * NN + j] > 0) {
      const void* aq = (r < NAQ) ? ((j < NAQ) ? a_aa : a_am)
                                 : ((j < NAQ) ? a_ma : a_mm);
      float s = ldf(adjn, r * NN + j, bf) * ldf(aq, 248, bf);
      for (int c = 0; c < CTXD; ++c) {
        s += ldf(ctx, r * CTXD + c, bf) * ldf(aq, 64 + c, bf);
        s += ldf(ctx, j * CTXD + c, bf) * ldf(aq, 188 + c, bf);
      }
      v = s * LOG2E;
    }
    ws[WS_EB_F + e] = v;
  }
}

// =======================================================================
// main: one WAVE = one batch element; single barrier; block-cooperative
// embedding pre-gather into LDS (replaces divergent per-wave gather)
// =======================================================================
__global__ __launch_bounds__(512, 4) void hga_main(
    const void* __restrict__ aqi_inp, const void* __restrict__ meo_inp,
    const void* __restrict__ ctx,
    const void* __restrict__ aqi_idE, const void* __restrict__ aqi_monthE,
    const void* __restrict__ aqi_weekdayE, const void* __restrict__ aqi_hourE,
    const void* __restrict__ meo_windE, const void* __restrict__ meo_idE,
    const void* __restrict__ meo_monthE, const void* __restrict__ meo_weekdayE,
    const void* __restrict__ meo_hourE,
    const int* __restrict__ aqi_ex, const int* __restrict__ meo_ex,
    const float* __restrict__ ws, void* __restrict__ out, int B)
{
  __shared__ __align__(16) u16  sWtA[64 * 40];      // padded stride 40
  __shared__ __align__(16) u16  sWtPhi[16 * 72];    // padded stride 72 (rows>=4 zero)
  __shared__ __align__(16) u16  sWtPlo[16 * 72];
  __shared__ __align__(16) float sEB[64 * 68];      // padded stride 68, rows>=53 sentinel
  __shared__ __align__(16) float sSVW[WAVES * 256]; // per wave: S[64][2] then T[64][2]
  // per element 1136 u16: aqi r*16 (hi8,lo8); meo 560 + ri*32 (f1 hi,lo, f2 hi,lo)
  __shared__ __align__(16) u16  sEMB[WAVES * 1136];

  const int t = threadIdx.x;
  const bool bf = (ws[WS_FLAG] != 0.f);
  const int wv = t >> 6, lane = t & 63;
  const int mm = lane & 15, q4 = lane >> 4;
  const int b = blockIdx.x * WAVES + wv;
  const bool valid = (b < B);

  // ---- input A-fragments straight from global (issue early) ----
  s8v av0[4];
  const s8v zero8 = {0, 0, 0, 0, 0, 0, 0, 0};
#pragma unroll
  for (int i = 0; i < 4; ++i) {
    s8v v0 = zero8;
    const int r = 16 * i + mm;
    if (valid && r < NN) {
      if (r < NAQ) {
        if (q4 < 2) v0 = load_inp8(aqi_inp, ((long)b * NAQ + r) * 16 + q4 * 8, bf);
      } else {
        if (q4 >= 2) v0 = load_inp8(meo_inp, ((long)b * NME + (r - NAQ)) * 16 + (q4 - 2) * 8, bf);
      }
    }
    av0[i] = v0;
  }

  // ---- block-cooperative embedding gather: one thread per (elem,row) ----
  if (t < WAVES * NN) {
    const int el = t / NN;
    const int r  = t - el * NN;
    const int bb = blockIdx.x * WAVES + el;
    if (bb < B) {
      u16* dst = sEMB + el * 1136;
      union { s8v s; uint4 u; } H, L;
      if (r < NAQ) {
        const int4 ix = *(const int4*)(aqi_ex + ((long)bb * NAQ + r) * 4);
        float e[8];
        e[0] = ldf(aqi_idE,      ix.x * 2, bf);  e[1] = ldf(aqi_idE,      ix.x * 2 + 1, bf);
        e[2] = ldf(aqi_monthE,   ix.y * 2, bf);  e[3] = ldf(aqi_monthE,   ix.y * 2 + 1, bf);
        e[4] = ldf(aqi_weekdayE, ix.z * 2, bf);  e[5] = ldf(aqi_weekdayE, ix.z * 2 + 1, bf);
        e[6] = ldf(aqi_hourE,    ix.w * 2, bf);  e[7] = ldf(aqi_hourE,    ix.w * 2 + 1, bf);
        pack_hl(e, &H.s, &L.s);
        *(uint4*)(dst + r * 16)     = H.u;
        *(uint4*)(dst + r * 16 + 8) = L.u;
      } else {
        const int ri = r - NAQ;
        const int* ix = meo_ex + ((long)bb * NME + ri) * 5;
        float e[8];
        e[0] = ldf(meo_windE,    ix[0] * 2, bf); e[1] = ldf(meo_windE,    ix[0] * 2 + 1, bf);
        e[2] = ldf(meo_idE,      ix[1] * 2, bf); e[3] = ldf(meo_idE,      ix[1] * 2 + 1, bf);
        e[4] = ldf(meo_monthE,   ix[2] * 2, bf); e[5] = ldf(meo_monthE,   ix[2] * 2 + 1, bf);
        e[6] = ldf(meo_weekdayE, ix[3] * 2, bf); e[7] = ldf(meo_weekdayE, ix[3] * 2 + 1, bf);
        pack_hl(e, &H.s, &L.s);
        u16* d2 = dst + 560 + ri * 32;
        *(uint4*)(d2)     = H.u;
        *(uint4*)(d2 + 8) = L.u;
        float e2[8] = {0.f, 0.f, 0.f, 0.f, 0.f, 0.f, 0.f, 0.f};
        e2[0] = ldf(meo_hourE, ix[4] * 2, bf);
        e2[1] = ldf(meo_hourE, ix[4] * 2 + 1, bf);
        pack_hl(e2, &H.s, &L.s);
        *(uint4*)(d2 + 16) = H.u;
        *(uint4*)(d2 + 24) = L.u;
      }
    }
  }

  // ---- one-time shared staging ----
  for (int u = t; u < 256; u += 512) {               // WtA: 64 rows x 4 units
    int row = u >> 2, c = u & 3;
    *(uint4*)(sWtA + row * 40 + c * 8) = ((const uint4*)ws)[u];
  }
  for (int u = t; u < 256; u += 512) {               // WtP hi/lo: 16 rows x 8 units
    int half = u >> 7, u2 = u & 127;
    int row = u2 >> 3, c = u2 & 7;
    uint4 v = make_uint4(0, 0, 0, 0);
    if (row < 4) v = ((const uint4*)ws)[256 + half * 32 + row * 8 + c];
    u16* dst = half ? sWtPlo : sWtPhi;
    *(uint4*)(dst + row * 72 + c * 8) = v;
  }
  for (int u = t; u < 1024; u += 512) {              // EB2: 64 rows x 16 units
    int r = u >> 4, f = u & 15;
    float4 v4 = make_float4(1e30f, 1e30f, 1e30f, 1e30f);
    if (r < NN) v4 = *(const float4*)(ws + WS_EB_F + r * 64 + f * 4);
    *(float4*)(sEB + r * 68 + f * 4) = v4;
  }
  __syncthreads();
  if (!valid) return;

  // ---- embedding fragments from LDS (contiguous b128 reads) ----
  s8v a1h[4], a1l[4];
  const u16* myemb = sEMB + wv * 1136;
#pragma unroll
  for (int i = 0; i < 4; ++i) {
    a1h[i] = zero8; a1l[i] = zero8;
    const int r = 16 * i + mm;
    if (r < NN) {
      if (r < NAQ) {
        if (q4 == 0) { a1h[i] = ld_fragu(myemb + r * 16); a1l[i] = ld_fragu(myemb + r * 16 + 8); }
      } else {
        const int ri = r - NAQ;
        if (q4 == 1)      { a1h[i] = ld_fragu(myemb + 560 + ri * 32);      a1l[i] = ld_fragu(myemb + 560 + ri * 32 + 8); }
        else if (q4 == 2) { a1h[i] = ld_fragu(myemb + 560 + ri * 32 + 16); a1l[i] = ld_fragu(myemb + 560 + ri * 32 + 24); }
      }
    }
  }

  // ---- projections via MFMA (hi/lo split weights -> ~fp32 accuracy) ----
  {
    s8v bh0 = ld_fragu(sWtPhi + mm * 72 + q4 * 8);
    s8v bh1 = ld_fragu(sWtPhi + mm * 72 + (4 + q4) * 8);
    s8v bl0 = ld_fragu(sWtPlo + mm * 72 + q4 * 8);
    s8v bl1 = ld_fragu(sWtPlo + mm * 72 + (4 + q4) * 8);
    f4v pacc[4];
#pragma unroll
    for (int i = 0; i < 4; ++i) {
      f4v a = {0.f, 0.f, 0.f, 0.f};
      a = __builtin_amdgcn_mfma_f32_16x16x32_bf16(av0[i], bh0, a, 0, 0, 0);
      a = __builtin_amdgcn_mfma_f32_16x16x32_bf16(av0[i], bl0, a, 0, 0, 0);
      a = __builtin_amdgcn_mfma_f32_16x16x32_bf16(a1h[i], bh1, a, 0, 0, 0);
      a = __builtin_amdgcn_mfma_f32_16x16x32_bf16(a1h[i], bl1, a, 0, 0, 0);
      if (!bf)
        a = __builtin_amdgcn_mfma_f32_16x16x32_bf16(a1l[i], bh1, a, 0, 0, 0);
      pacc[i] = a;
    }
    if (mm < 4) {
      float* wbase = sSVW + wv * 256 + ((mm >= 2) ? 128 : 0) + (mm & 1);
#pragma unroll
      for (int i = 0; i < 4; ++i)
#pragma unroll
        for (int reg = 0; reg < 4; ++reg) {
          int row = 16 * i + q4 * 4 + reg;
          wbase[row * 2] = pacc[i][reg];
        }
    }
  }
  asm volatile("s_waitcnt lgkmcnt(0)" ::: "memory");
  __builtin_amdgcn_sched_barrier(0);

  // ---- softmax fully in-register (exp2 domain), GEMM2 B-frag layout ----
  const float* sv = sSVW + wv * 256;
  u32 paw[4][8];
#pragma unroll
  for (int i = 0; i < 4; ++i) {
    const int r = 16 * i + mm;
    const bool rA = (r < NAQ);
    const int tsel = rA ? 0 : 1;
    float2 sp = *(const float2*)(sv + r * 2);
    const float* ebr = sEB + r * 68;
    float4 ea  = *(const float4*)(ebr + q4 * 8);
    float4 eb_ = *(const float4*)(ebr + q4 * 8 + 4);
    float4 ec  = *(const float4*)(ebr + 32 + q4 * 8);
    float4 ed  = *(const float4*)(ebr + 32 + q4 * 8 + 4);
    float ebv[16] = {ea.x, ea.y, ea.z, ea.w, eb_.x, eb_.y, eb_.z, eb_.w,
                     ec.x, ec.y, ec.z, ec.w, ed.x, ed.y, ed.z, ed.w};
    float v[16];
#pragma unroll
    for (int c = 0; c < 16; ++c) {
      const int j = (c < 8) ? (q4 * 8 + c) : (32 + q4 * 8 + (c - 8));
      float s = (j < NAQ) ? sp.x : sp.y;
      float tv = sv[128 + j * 2 + tsel];
      float x = s + tv + ebv[c];
      float lk = fmaxf(x, 0.2f * x);
      v[c] = (ebv[c] > 1e29f) ? -1.0e12f : lk;
    }
    float t0 = fmaxf(fmaxf(v[0], v[1]),  fmaxf(v[2], v[3]));
    float t1 = fmaxf(fmaxf(v[4], v[5]),  fmaxf(v[6], v[7]));
    float t2 = fmaxf(fmaxf(v[8], v[9]),  fmaxf(v[10], v[11]));
    float t3 = fmaxf(fmaxf(v[12], v[13]), fmaxf(v[14], v[15]));
    float m = fmaxf(fmaxf(t0, t1), fmaxf(t2, t3));
    m = fmaxf(m, __shfl_xor(m, 16));
    m = fmaxf(m, __shfl_xor(m, 32));
    float sum = 0.f;
#pragma unroll
    for (int c = 0; c < 16; ++c) { float p = exp2f(v[c] - m); v[c] = p; sum += p; }
    sum += __shfl_xor(sum, 16);
    sum += __shfl_xor(sum, 32);
    const float rinv = 1.f / sum;
#pragma unroll
    for (int w = 0; w < 8; ++w) {
      const int c0 = (w >> 2) * 8 + (w & 3) * 2;
      paw[i][w] = pk2(v[c0] * rinv, v[c0 + 1] * rinv);
    }
  }

  // ---- GEMM1 (attri) + in-register transpose + swapped GEMM2 (O^T) ----
  const u32 baseA = (u32)b * (NAQ * 64u);
  const u32 baseM = (u32)B * (NAQ * 64u) + (u32)b * (NME * 64u);
  const int srcA = (2 * (q4 & 1)) * 16 + mm;
  const int srcB = srcA + 16;
  const bool hs = (q4 >= 2);
  __builtin_amdgcn_s_setprio(1);
#pragma unroll
  for (int nt = 0; nt < 4; ++nt) {
    s8v bw = ld_fragu(sWtA + (16 * nt + mm) * 40 + q4 * 8);
    f4v ag[4];
#pragma unroll
    for (int i = 0; i < 4; ++i) {
      f4v z = {0.f, 0.f, 0.f, 0.f};
      ag[i] = __builtin_amdgcn_mfma_f32_16x16x32_bf16(av0[i], bw, z, 0, 0, 0);
    }
    u32 p0[4], p1[4];
#pragma unroll
    for (int i = 0; i < 4; ++i) {
      p0[i] = pk2(ag[i][0], ag[i][1]);
      p1[i] = pk2(ag[i][2], ag[i][3]);
    }
    union { u32 u[4]; s8v s; } W0, W1;
    u32 x0, x1;
    x0 = (u32)__shfl((int)p0[0], srcA); x1 = (u32)__shfl((int)p0[1], srcA); W0.u[0] = hs ? x1 : x0;
    x0 = (u32)__shfl((int)p1[0], srcA); x1 = (u32)__shfl((int)p1[1], srcA); W0.u[1] = hs ? x1 : x0;
    x0 = (u32)__shfl((int)p0[0], srcB); x1 = (u32)__shfl((int)p0[1], srcB); W0.u[2] = hs ? x1 : x0;
    x0 = (u32)__shfl((int)p1[0], srcB); x1 = (u32)__shfl((int)p1[1], srcB); W0.u[3] = hs ? x1 : x0;
    x0 = (u32)__shfl((int)p0[2], srcA); x1 = (u32)__shfl((int)p0[3], srcA); W1.u[0] = hs ? x1 : x0;
    x0 = (u32)__shfl((int)p1[2], srcA); x1 = (u32)__shfl((int)p1[3], srcA); W1.u[1] = hs ? x1 : x0;
    x0 = (u32)__shfl((int)p0[2], srcB); x1 = (u32)__shfl((int)p0[3], srcB); W1.u[2] = hs ? x1 : x0;
    x0 = (u32)__shfl((int)p1[2], srcB); x1 = (u32)__shfl((int)p1[3], srcB); W1.u[3] = hs ? x1 : x0;
    s8v bt0 = W0.s, bt1 = W1.s;
#pragma unroll
    for (int i = 0; i < 4; ++i) {
      union { u32 u[4]; s8v s; } A0, A1;
      A0.u[0] = paw[i][0]; A0.u[1] = paw[i][1]; A0.u[2] = paw[i][2]; A0.u[3] = paw[i][3];
      A1.u[0] = paw[i][4]; A1.u[1] = paw[i][5]; A1.u[2] = paw[i][6]; A1.u[3] = paw[i][7];
      f4v acc = {0.f, 0.f, 0.f, 0.f};
      acc = __builtin_amdgcn_mfma_f32_16x16x32_bf16(bt0, A0.s, acc, 0, 0, 0);
      acc = __builtin_amdgcn_mfma_f32_16x16x32_bf16(bt1, A1.s, acc, 0, 0, 0);
      const int r = 16 * i + mm;
      if (r < NN) {
        u32 off = ((r < NAQ) ? (baseA + (u32)r * 64u)
                             : (baseM + (u32)(r - NAQ) * 64u))
                  + 16u * (u32)nt + (u32)(q4 * 4);
        if (bf) {
          uint2 pkv;
          pkv.x = pk2(acc[0], acc[1]);
          pkv.y = pk2(acc[2], acc[3]);
          *(uint2*)((u16*)out + off) = pkv;
        } else {
          union { f4v v; float4 f; } cv; cv.v = acc;
          *(float4*)((float*)out + off) = cv.f;
        }
      }
    }
  }
  __builtin_amdgcn_s_setprio(0);
}

extern "C" void kernel_launch(void* const* d_in, const int* in_sizes, int n_in,
                              void* d_out, int out_size, void* d_ws, size_t ws_size,
                              hipStream_t stream)
{
  const void* aqi_inp      = d_in[0];
  const void* meo_inp      = d_in[1];
  const void* ctx          = d_in[2];
  const void* adjn         = d_in[3];
  const void* aqi_idE      = d_in[4];
  const void* aqi_monthE   = d_in[5];
  const void* aqi_weekdayE = d_in[6];
  const void* aqi_hourE    = d_in[7];
  const void* meo_windE    = d_in[8];
  const void* meo_idE      = d_in[9];
  const void* meo_monthE   = d_in[10];
  const void* meo_weekdayE = d_in[11];
  const void* meo_hourE    = d_in[12];
  const void* Wxa          = d_in[13];
  const void* Wxm          = d_in[14];
  const void* Wua          = d_in[15];
  const void* Wum          = d_in[16];
  const void* a_aa         = d_in[17];
  const void* a_am         = d_in[18];
  const void* a_ma         = d_in[19];
  const void* a_mm         = d_in[20];
  const int*  aqi_ex       = (const int*)d_in[21];
  const int*  meo_ex       = (const int*)d_in[22];
  float* ws = (float*)d_ws;
  const int B = in_sizes[0] / (NAQ * 16);

  hipLaunchKernelGGL(prep_kernel, dim3((5952 + 255) / 256), dim3(256), 0, stream,
                     ctx, adjn, Wxa, Wxm, Wua, Wum, a_aa, a_am, a_ma, a_mm,
                     (const int*)d_in[23], ws);
  hipLaunchKernelGGL(hga_main, dim3((B + WAVES - 1) / WAVES), dim3(512), 0, stream,
                     aqi_inp, meo_inp, ctx, aqi_idE, aqi_monthE, aqi_weekdayE, aqi_hourE,
                     meo_windE, meo_idE, meo_monthE, meo_weekdayE, meo_hourE,
                     aqi_ex, meo_ex, ws, d_out, B);
}

// Round 8
// 142.854 us; speedup vs baseline: 1.1173x; 1.0681x over previous
//
#include <hip/hip_runtime.h>

#define NAQ 35
#define NME 18
#define NN  53
#define FD  64
#define CTXD 60
#define WAVES 8

typedef unsigned int   u32;
typedef unsigned short u16;
typedef short s8v __attribute__((ext_vector_type(8)));
typedef float f4v __attribute__((ext_vector_type(4)));

// ---- ws float layout ----
//  [0,1024)    : WtA  u16[64][32]   Wt[n][k] = k<16 ? Wxa[k][n] : Wxm[k-16][n]
//  [1024,1152) : WtP hi u16[4][64]  proj weights * log2e, bf16 high
//  [1152,1280) : WtP lo u16[4][64]  bf16 residual
//  [1280,4672) : EB2 f32[53][64]    (bias + ctx dots) * log2e; sentinel 1e30
//  [4672]      : bf16-input flag
#define WS_EB_F  1280
#define WS_FLAG  4672
#define LOG2E    1.44269504f

__device__ __forceinline__ float ldf(const void* p, long i, bool bf) {
  if (bf) { u16 h = ((const u16*)p)[i]; return __uint_as_float(((u32)h) << 16); }
  return ((const float*)p)[i];
}
__device__ __forceinline__ u16 f2bf(float f) {
  u32 u = __float_as_uint(f);
  return (u16)((u + 0x7FFFu + ((u >> 16) & 1u)) >> 16);
}
__device__ __forceinline__ float bf2f(u16 h) {
  return __uint_as_float(((u32)h) << 16);
}
__device__ __forceinline__ u32 pk2(float a, float b) {
  return (u32)f2bf(a) | ((u32)f2bf(b) << 16);
}
__device__ __forceinline__ bool sniff_bf16(const void* ctx) {
  const u32* w = (const u32*)ctx;
  bool ok = true;
#pragma unroll
  for (int k = 0; k < 32; ++k) {
    u32 e = (w[k] >> 7) & 0xFFu;
    ok = ok && (e >= 96u && e <= 160u);
  }
  return ok;
}
__device__ __forceinline__ s8v ld_fragu(const u16* p) {
  union { float4 f; s8v s; } u;
  u.f = *(const float4*)(const void*)p;
  return u.s;
}
__device__ __forceinline__ s8v pack8f(float4 a, float4 b) {
  union { u32 u[4]; s8v s; } U;
  U.u[0] = pk2(a.x, a.y);
  U.u[1] = pk2(a.z, a.w);
  U.u[2] = pk2(b.x, b.y);
  U.u[3] = pk2(b.z, b.w);
  return U.s;
}
__device__ __forceinline__ s8v load_inp8(const void* p, long idx, bool bf) {
  if (bf) {
    union { uint4 u; s8v s; } U;
    U.u = *(const uint4*)((const u16*)p + idx);
    return U.s;
  }
  float4 f0 = *(const float4*)((const float*)p + idx);
  float4 f1 = *(const float4*)((const float*)p + idx + 4);
  return pack8f(f0, f1);
}
__device__ __forceinline__ void pack_hl(const float* e, s8v* hi, s8v* lo) {
  union { u32 u[4]; s8v s; } H, L;
#pragma unroll
  for (int w = 0; w < 4; ++w) {
    u16 h0 = f2bf(e[2*w]), h1 = f2bf(e[2*w+1]);
    float l0 = e[2*w] - bf2f(h0), l1 = e[2*w+1] - bf2f(h1);
    H.u[w] = (u32)h0 | ((u32)h1 << 16);
    L.u[w] = (u32)f2bf(l0) | ((u32)f2bf(l1) << 16);
  }
  *hi = H.s; *lo = L.s;
}
__device__ __forceinline__ void avsel(int tr,
    const void* a_aa, const void* a_am, const void* a_ma, const void* a_mm,
    const void** av, int* off) {
  switch (tr) {
    case 0: *av = a_aa; *off = 0;   break;
    case 1: *av = a_am; *off = 0;   break;
    case 2: *av = a_aa; *off = 124; break;
    case 3: *av = a_ma; *off = 124; break;
    case 4: *av = a_ma; *off = 0;   break;
    case 5: *av = a_mm; *off = 0;   break;
    case 6: *av = a_am; *off = 124; break;
    default:*av = a_mm; *off = 124; break;
  }
}

// =======================================================================
// prep: batch-invariant tables -> ws.  WAVE-PER-DOT parallelization:
//   waves [0,32)      WtA copy (lane-per-entry)
//   waves [32,288)    WtP (role,k): 64-lane dot + shfl reduce, hi+lo from one dot
//   waves [288,3680)  EB2 (r,j): lanes 0..59 ctx products + shfl reduce
// 920 blocks x 256 thr (vs old 26 blocks) -> full-machine TLP.
// =======================================================================
__global__ void prep_kernel(
    const void* __restrict__ ctx, const void* __restrict__ adjn,
    const void* __restrict__ Wxa, const void* __restrict__ Wxm,
    const void* __restrict__ Wua, const void* __restrict__ Wum,
    const void* __restrict__ a_aa, const void* __restrict__ a_am,
    const void* __restrict__ a_ma, const void* __restrict__ a_mm,
    const int* __restrict__ adj, float* __restrict__ ws)
{
  const bool bf = sniff_bf16(ctx);
  const int lane = threadIdx.x & 63;
  const int W = blockIdx.x * 4 + (threadIdx.x >> 6);
  if (W == 0 && lane == 0) ws[WS_FLAG] = bf ? 1.f : 0.f;
  if (W < 32) {                        // WtA[n][k] bf16: lane-per-entry
    int tid = W * 64 + lane;
    int n = tid >> 5, kk = tid & 31;
    float v = (kk < 16) ? ldf(Wxa, kk * 64 + n, bf)
                        : ldf(Wxm, (kk - 16) * 64 + n, bf);
    ((u16*)ws)[tid] = f2bf(v);
    return;
  }
  if (W < 288) {                       // WtP (role,k): wave dot, write hi+lo
    const int entry = W - 32;          // 0..255
    const int role = entry >> 6, k = entry & 63;
    const void* Wu = nullptr; int kk = -1, tr = 0;
    if (k < 16)      { Wu = Wua; kk = k;      tr = role;     }
    else if (k < 32) { Wu = Wum; kk = k - 16; tr = 4 + role; }
    else if (k < 40) { Wu = Wua; kk = k - 16; tr = role;     }   // 16+(k-32)
    else if (k < 50) { Wu = Wum; kk = k - 24; tr = 4 + role; }   // 16+(k-40)
    float w = 0.f;
    if (kk >= 0) {
      const void* av; int off;
      avsel(tr, a_aa, a_am, a_ma, a_mm, &av, &off);
      float p = ldf(Wu, kk * 64 + lane, bf) * ldf(av, off + lane, bf);
      p += __shfl_xor(p, 1);  p += __shfl_xor(p, 2);  p += __shfl_xor(p, 4);
      p += __shfl_xor(p, 8);  p += __shfl_xor(p, 16); p += __shfl_xor(p, 32);
      w = p * LOG2E;
    }
    if (lane == 0) {
      u16 hi = f2bf(w);
      ((u16*)ws)[2048 + entry] = hi;
      ((u16*)ws)[2304 + entry] = f2bf(w - bf2f(hi));
    }
    return;
  }
  if (W < 3680) {                      // EB2 (r,j): wave dot
    const int entry = W - 288;         // 0..3391
    const int r = entry >> 6, j = entry & 63;
    float v = 1e30f;
    if (j < NN && adj[r * NN + j] > 0) {
      const void* aq = (r < NAQ) ? ((j < NAQ) ? a_aa : a_am)
                                 : ((j < NAQ) ? a_ma : a_mm);
      float p = 0.f;
      if (lane < CTXD)
        p = ldf(ctx, r * CTXD + lane, bf) * ldf(aq, 64 + lane, bf)
          + ldf(ctx, j * CTXD + lane, bf) * ldf(aq, 188 + lane, bf);
      p += __shfl_xor(p, 1);  p += __shfl_xor(p, 2);  p += __shfl_xor(p, 4);
      p += __shfl_xor(p, 8);  p += __shfl_xor(p, 16); p += __shfl_xor(p, 32);
      v = (ldf(adjn, r * NN + j, bf) * ldf(aq, 248, bf) + p) * LOG2E;
    }
    if (lane == 0) ws[WS_EB_F + entry] = v;
  }
}

// =======================================================================
// main: one WAVE = one batch element; single barrier; block-cooperative
// embedding pre-gather into LDS (unchanged from round 7 — passing)
// =======================================================================
__global__ __launch_bounds__(512, 4) void hga_main(
    const void* __restrict__ aqi_inp, const void* __restrict__ meo_inp,
    const void* __restrict__ ctx,
    const void* __restrict__ aqi_idE, const void* __restrict__ aqi_monthE,
    const void* __restrict__ aqi_weekdayE, const void* __restrict__ aqi_hourE,
    const void* __restrict__ meo_windE, const void* __restrict__ meo_idE,
    const void* __restrict__ meo_monthE, const void* __restrict__ meo_weekdayE,
    const void* __restrict__ meo_hourE,
    const int* __restrict__ aqi_ex, const int* __restrict__ meo_ex,
    const float* __restrict__ ws, void* __restrict__ out, int B)
{
  __shared__ __align__(16) u16  sWtA[64 * 40];      // padded stride 40
  __shared__ __align__(16) u16  sWtPhi[16 * 72];    // padded stride 72 (rows>=4 zero)
  __shared__ __align__(16) u16  sWtPlo[16 * 72];
  __shared__ __align__(16) float sEB[64 * 68];      // padded stride 68, rows>=53 sentinel
  __shared__ __align__(16) float sSVW[WAVES * 256]; // per wave: S[64][2] then T[64][2]
  __shared__ __align__(16) u16  sEMB[WAVES * 1136];

  const int t = threadIdx.x;
  const bool bf = (ws[WS_FLAG] != 0.f);
  const int wv = t >> 6, lane = t & 63;
  const int mm = lane & 15, q4 = lane >> 4;
  const int b = blockIdx.x * WAVES + wv;
  const bool valid = (b < B);

  // ---- input A-fragments straight from global (issue early) ----
  s8v av0[4];
  const s8v zero8 = {0, 0, 0, 0, 0, 0, 0, 0};
#pragma unroll
  for (int i = 0; i < 4; ++i) {
    s8v v0 = zero8;
    const int r = 16 * i + mm;
    if (valid && r < NN) {
      if (r < NAQ) {
        if (q4 < 2) v0 = load_inp8(aqi_inp, ((long)b * NAQ + r) * 16 + q4 * 8, bf);
      } else {
        if (q4 >= 2) v0 = load_inp8(meo_inp, ((long)b * NME + (r - NAQ)) * 16 + (q4 - 2) * 8, bf);
      }
    }
    av0[i] = v0;
  }

  // ---- block-cooperative embedding gather: one thread per (elem,row) ----
  if (t < WAVES * NN) {
    const int el = t / NN;
    const int r  = t - el * NN;
    const int bb = blockIdx.x * WAVES + el;
    if (bb < B) {
      u16* dst = sEMB + el * 1136;
      union { s8v s; uint4 u; } H, L;
      if (r < NAQ) {
        const int4 ix = *(const int4*)(aqi_ex + ((long)bb * NAQ + r) * 4);
        float e[8];
        e[0] = ldf(aqi_idE,      ix.x * 2, bf);  e[1] = ldf(aqi_idE,      ix.x * 2 + 1, bf);
        e[2] = ldf(aqi_monthE,   ix.y * 2, bf);  e[3] = ldf(aqi_monthE,   ix.y * 2 + 1, bf);
        e[4] = ldf(aqi_weekdayE, ix.z * 2, bf);  e[5] = ldf(aqi_weekdayE, ix.z * 2 + 1, bf);
        e[6] = ldf(aqi_hourE,    ix.w * 2, bf);  e[7] = ldf(aqi_hourE,    ix.w * 2 + 1, bf);
        pack_hl(e, &H.s, &L.s);
        *(uint4*)(dst + r * 16)     = H.u;
        *(uint4*)(dst + r * 16 + 8) = L.u;
      } else {
        const int ri = r - NAQ;
        const int* ix = meo_ex + ((long)bb * NME + ri) * 5;
        float e[8];
        e[0] = ldf(meo_windE,    ix[0] * 2, bf); e[1] = ldf(meo_windE,    ix[0] * 2 + 1, bf);
        e[2] = ldf(meo_idE,      ix[1] * 2, bf); e[3] = ldf(meo_idE,      ix[1] * 2 + 1, bf);
        e[4] = ldf(meo_monthE,   ix[2] * 2, bf); e[5] = ldf(meo_monthE,   ix[2] * 2 + 1, bf);
        e[6] = ldf(meo_weekdayE, ix[3] * 2, bf); e[7] = ldf(meo_weekdayE, ix[3] * 2 + 1, bf);
        pack_hl(e, &H.s, &L.s);
        u16* d2 = dst + 560 + ri * 32;
        *(uint4*)(d2)     = H.u;
        *(uint4*)(d2 + 8) = L.u;
        float e2[8] = {0.f, 0.f, 0.f, 0.f, 0.f, 0.f, 0.f, 0.f};
        e2[0] = ldf(meo_hourE, ix[4] * 2, bf);
        e2[1] = ldf(meo_hourE, ix[4] * 2 + 1, bf);
        pack_hl(e2, &H.s, &L.s);
        *(uint4*)(d2 + 16) = H.u;
        *(uint4*)(d2 + 24) = L.u;
      }
    }
  }

  // ---- one-time shared staging ----
  for (int u = t; u < 256; u += 512) {               // WtA: 64 rows x 4 units
    int row = u >> 2, c = u & 3;
    *(uint4*)(sWtA + row * 40 + c * 8) = ((const uint4*)ws)[u];
  }
  for (int u = t; u < 256; u += 512) {               // WtP hi/lo: 16 rows x 8 units
    int half = u >> 7, u2 = u & 127;
    int row = u2 >> 3, c = u2 & 7;
    uint4 v = make_uint4(0, 0, 0, 0);
    if (row < 4) v = ((const uint4*)ws)[256 + half * 32 + row * 8 + c];
    u16* dst = half ? sWtPlo : sWtPhi;
    *(uint4*)(dst + row * 72 + c * 8) = v;
  }
  for (int u = t; u < 1024; u += 512) {              // EB2: 64 rows x 16 units
    int r = u >> 4, f = u & 15;
    float4 v4 = make_float4(1e30f, 1e30f, 1e30f, 1e30f);
    if (r < NN) v4 = *(const float4*)(ws + WS_EB_F + r * 64 + f * 4);
    *(float4*)(sEB + r * 68 + f * 4) = v4;
  }
  __syncthreads();
  if (!valid) return;

  // ---- embedding fragments from LDS (contiguous b128 reads) ----
  s8v a1h[4], a1l[4];
  const u16* myemb = sEMB + wv * 1136;
#pragma unroll
  for (int i = 0; i < 4; ++i) {
    a1h[i] = zero8; a1l[i] = zero8;
    const int r = 16 * i + mm;
    if (r < NN) {
      if (r < NAQ) {
        if (q4 == 0) { a1h[i] = ld_fragu(myemb + r * 16); a1l[i] = ld_fragu(myemb + r * 16 + 8); }
      } else {
        const int ri = r - NAQ;
        if (q4 == 1)      { a1h[i] = ld_fragu(myemb + 560 + ri * 32);      a1l[i] = ld_fragu(myemb + 560 + ri * 32 + 8); }
        else if (q4 == 2) { a1h[i] = ld_fragu(myemb + 560 + ri * 32 + 16); a1l[i] = ld_fragu(myemb + 560 + ri * 32 + 24); }
      }
    }
  }

  // ---- projections via MFMA (hi/lo split weights -> ~fp32 accuracy) ----
  {
    s8v bh0 = ld_fragu(sWtPhi + mm * 72 + q4 * 8);
    s8v bh1 = ld_fragu(sWtPhi + mm * 72 + (4 + q4) * 8);
    s8v bl0 = ld_fragu(sWtPlo + mm * 72 + q4 * 8);
    s8v bl1 = ld_fragu(sWtPlo + mm * 72 + (4 + q4) * 8);
    f4v pacc[4];
#pragma unroll
    for (int i = 0; i < 4; ++i) {
      f4v a = {0.f, 0.f, 0.f, 0.f};
      a = __builtin_amdgcn_mfma_f32_16x16x32_bf16(av0[i], bh0, a, 0, 0, 0);
      a = __builtin_amdgcn_mfma_f32_16x16x32_bf16(av0[i], bl0, a, 0, 0, 0);
      a = __builtin_amdgcn_mfma_f32_16x16x32_bf16(a1h[i], bh1, a, 0, 0, 0);
      a = __builtin_amdgcn_mfma_f32_16x16x32_bf16(a1h[i], bl1, a, 0, 0, 0);
      if (!bf)
        a = __builtin_amdgcn_mfma_f32_16x16x32_bf16(a1l[i], bh1, a, 0, 0, 0);
      pacc[i] = a;
    }
    if (mm < 4) {
      float* wbase = sSVW + wv * 256 + ((mm >= 2) ? 128 : 0) + (mm & 1);
#pragma unroll
      for (int i = 0; i < 4; ++i)
#pragma unroll
        for (int reg = 0; reg < 4; ++reg) {
          int row = 16 * i + q4 * 4 + reg;
          wbase[row * 2] = pacc[i][reg];
        }
    }
  }
  asm volatile("s_waitcnt lgkmcnt(0)" ::: "memory");
  __builtin_amdgcn_sched_barrier(0);

  // ---- softmax fully in-register (exp2 domain), GEMM2 B-frag layout ----
  const float* sv = sSVW + wv * 256;
  u32 paw[4][8];
#pragma unroll
  for (int i = 0; i < 4; ++i) {
    const int r = 16 * i + mm;
    const bool rA = (r < NAQ);
    const int tsel = rA ? 0 : 1;
    float2 sp = *(const float2*)(sv + r * 2);
    const float* ebr = sEB + r * 68;
    float4 ea  = *(const float4*)(ebr + q4 * 8);
    float4 eb_ = *(const float4*)(ebr + q4 * 8 + 4);
    float4 ec  = *(const float4*)(ebr + 32 + q4 * 8);
    float4 ed  = *(const float4*)(ebr + 32 + q4 * 8 + 4);
    float ebv[16] = {ea.x, ea.y, ea.z, ea.w, eb_.x, eb_.y, eb_.z, eb_.w,
                     ec.x, ec.y, ec.z, ec.w, ed.x, ed.y, ed.z, ed.w};
    float v[16];
#pragma unroll
    for (int c = 0; c < 16; ++c) {
      const int j = (c < 8) ? (q4 * 8 + c) : (32 + q4 * 8 + (c - 8));
      float s = (j < NAQ) ? sp.x : sp.y;
      float tv = sv[128 + j * 2 + tsel];
      float x = s + tv + ebv[c];
      float lk = fmaxf(x, 0.2f * x);
      v[c] = (ebv[c] > 1e29f) ? -1.0e12f : lk;
    }
    float t0 = fmaxf(fmaxf(v[0], v[1]),  fmaxf(v[2], v[3]));
    float t1 = fmaxf(fmaxf(v[4], v[5]),  fmaxf(v[6], v[7]));
    float t2 = fmaxf(fmaxf(v[8], v[9]),  fmaxf(v[10], v[11]));
    float t3 = fmaxf(fmaxf(v[12], v[13]), fmaxf(v[14], v[15]));
    float m = fmaxf(fmaxf(t0, t1), fmaxf(t2, t3));
    m = fmaxf(m, __shfl_xor(m, 16));
    m = fmaxf(m, __shfl_xor(m, 32));
    float sum = 0.f;
#pragma unroll
    for (int c = 0; c < 16; ++c) { float p = exp2f(v[c] - m); v[c] = p; sum += p; }
    sum += __shfl_xor(sum, 16);
    sum += __shfl_xor(sum, 32);
    const float rinv = 1.f / sum;
#pragma unroll
    for (int w = 0; w < 8; ++w) {
      const int c0 = (w >> 2) * 8 + (w & 3) * 2;
      paw[i][w] = pk2(v[c0] * rinv, v[c0 + 1] * rinv);
    }
  }

  // ---- GEMM1 (attri) + in-register transpose + swapped GEMM2 (O^T) ----
  const u32 baseA = (u32)b * (NAQ * 64u);
  const u32 baseM = (u32)B * (NAQ * 64u) + (u32)b * (NME * 64u);
  const int srcA = (2 * (q4 & 1)) * 16 + mm;
  const int srcB = srcA + 16;
  const bool hs = (q4 >= 2);
  __builtin_amdgcn_s_setprio(1);
#pragma unroll
  for (int nt = 0; nt < 4; ++nt) {
    s8v bw = ld_fragu(sWtA + (16 * nt + mm) * 40 + q4 * 8);
    f4v ag[4];
#pragma unroll
    for (int i = 0; i < 4; ++i) {
      f4v z = {0.f, 0.f, 0.f, 0.f};
      ag[i] = __builtin_amdgcn_mfma_f32_16x16x32_bf16(av0[i], bw, z, 0, 0, 0);
    }
    u32 p0[4], p1[4];
#pragma unroll
    for (int i = 0; i < 4; ++i) {
      p0[i] = pk2(ag[i][0], ag[i][1]);
      p1[i] = pk2(ag[i][2], ag[i][3]);
    }
    union { u32 u[4]; s8v s; } W0, W1;
    u32 x0, x1;
    x0 = (u32)__shfl((int)p0[0], srcA); x1 = (u32)__shfl((int)p0[1], srcA); W0.u[0] = hs ? x1 : x0;
    x0 = (u32)__shfl((int)p1[0], srcA); x1 = (u32)__shfl((int)p1[1], srcA); W0.u[1] = hs ? x1 : x0;
    x0 = (u32)__shfl((int)p0[0], srcB); x1 = (u32)__shfl((int)p0[1], srcB); W0.u[2] = hs ? x1 : x0;
    x0 = (u32)__shfl((int)p1[0], srcB); x1 = (u32)__shfl((int)p1[1], srcB); W0.u[3] = hs ? x1 : x0;
    x0 = (u32)__shfl((int)p0[2], srcA); x1 = (u32)__shfl((int)p0[3], srcA); W1.u[0] = hs ? x1 : x0;
    x0 = (u32)__shfl((int)p1[2], srcA); x1 = (u32)__shfl((int)p1[3], srcA); W1.u[1] = hs ? x1 : x0;
    x0 = (u32)__shfl((int)p0[2], srcB); x1 = (u32)__shfl((int)p0[3], srcB); W1.u[2] = hs ? x1 : x0;
    x0 = (u32)__shfl((int)p1[2], srcB); x1 = (u32)__shfl((int)p1[3], srcB); W1.u[3] = hs ? x1 : x0;
    s8v bt0 = W0.s, bt1 = W1.s;
#pragma unroll
    for (int i = 0; i < 4; ++i) {
      union { u32 u[4]; s8v s; } A0, A1;
      A0.u[0] = paw[i][0]; A0.u[1] = paw[i][1]; A0.u[2] = paw[i][2]; A0.u[3] = paw[i][3];
      A1.u[0] = paw[i][4]; A1.u[1] = paw[i][5]; A1.u[2] = paw[i][6]; A1.u[3] = paw[i][7];
      f4v acc = {0.f, 0.f, 0.f, 0.f};
      acc = __builtin_amdgcn_mfma_f32_16x16x32_bf16(bt0, A0.s, acc, 0, 0, 0);
      acc = __builtin_amdgcn_mfma_f32_16x16x32_bf16(bt1, A1.s, acc, 0, 0, 0);
      const int r = 16 * i + mm;
      if (r < NN) {
        u32 off = ((r < NAQ) ? (baseA + (u32)r * 64u)
                             : (baseM + (u32)(r - NAQ) * 64u))
                  + 16u * (u32)nt + (u32)(q4 * 4);
        if (bf) {
          uint2 pkv;
          pkv.x = pk2(acc[0], acc[1]);
          pkv.y = pk2(acc[2], acc[3]);
          *(uint2*)((u16*)out + off) = pkv;
        } else {
          union { f4v v; float4 f; } cv; cv.v = acc;
          *(float4*)((float*)out + off) = cv.f;
        }
      }
    }
  }
  __builtin_amdgcn_s_setprio(0);
}

extern "C" void kernel_launch(void* const* d_in, const int* in_sizes, int n_in,
                              void* d_out, int out_size, void* d_ws, size_t ws_size,
                              hipStream_t stream)
{
  const void* aqi_inp      = d_in[0];
  const void* meo_inp      = d_in[1];
  const void* ctx          = d_in[2];
  const void* adjn         = d_in[3];
  const void* aqi_idE      = d_in[4];
  const void* aqi_monthE   = d_in[5];
  const void* aqi_weekdayE = d_in[6];
  const void* aqi_hourE    = d_in[7];
  const void* meo_windE    = d_in[8];
  const void* meo_idE      = d_in[9];
  const void* meo_monthE   = d_in[10];
  const void* meo_weekdayE = d_in[11];
  const void* meo_hourE    = d_in[12];
  const void* Wxa          = d_in[13];
  const void* Wxm          = d_in[14];
  const void* Wua          = d_in[15];
  const void* Wum          = d_in[16];
  const void* a_aa         = d_in[17];
  const void* a_am         = d_in[18];
  const void* a_ma         = d_in[19];
  const void* a_mm         = d_in[20];
  const int*  aqi_ex       = (const int*)d_in[21];
  const int*  meo_ex       = (const int*)d_in[22];
  float* ws = (float*)d_ws;
  const int B = in_sizes[0] / (NAQ * 16);

  // 3680 waves total -> 920 blocks of 4 waves
  hipLaunchKernelGGL(prep_kernel, dim3(920), dim3(256), 0, stream,
                     ctx, adjn, Wxa, Wxm, Wua, Wum, a_aa, a_am, a_ma, a_mm,
                     (const int*)d_in[23], ws);
  hipLaunchKernelGGL(hga_main, dim3((B + WAVES - 1) / WAVES), dim3(512), 0, stream,
                     aqi_inp, meo_inp, ctx, aqi_idE, aqi_monthE, aqi_weekdayE, aqi_hourE,
                     meo_windE, meo_idE, meo_monthE, meo_weekdayE, meo_hourE,
                     aqi_ex, meo_ex, ws, d_out, B);
}